// Round 7
// baseline (405.911 us; speedup 1.0000x reference)
//
#include <hip/hip_runtime.h>

// 4-layer GRU stack, B=4096, T=256. 256 persistent blocks x 768 threads,
// 16 batch rows per block (one M=16 MFMA tile).
//
// R7: BARRIER-FREE dataflow pipeline. Six rounds showed step time tracks the
// per-step block barrier (phase-locked waves), not issue counts. Now each of
// 10 rec waves owns a 16-unit slice of one layer for ALL timesteps:
//   w0..w3 = L0 units 0-15/16-31/32-47/48-63
//   w4,w5  = L2 units 0-15/16-31     (SIMD balance: w%4 = SIMD)
//   w6,w7  = L1 units 0-15/16-31
//   w8,w9  = L3 units 0-15/16-31
//   w10,w11 = x stagers (rows 0-7 / 8-15), 16-step chunks, 2-slot ring
// h streams live in depth-8 LDS rings; producer/consumer sync is per-wave
// LDS flags (volatile + __threadfence_block release/acquire) with spin +
// s_sleep. No __syncthreads in the hot path at all. Flags: [0..3]=L0,
// [4..5]=L1, [6..7]=L2, [8..9]=L3, [10..11]=x-stagers (chunk index).
// Spin conditions (wave at step t): own-layer min >= t-1 (partner halves of
// h_l(t-1)); input min >= t (or staged-chunk >= t/16 for L0); backpressure:
// next-layer min >= t-8 (ring reuse). All reference strictly earlier work ->
// deadlock-free; rings zeroed so t=0 reads h(-1)=0.

typedef __attribute__((ext_vector_type(8))) __bf16 bf16x8;
typedef __attribute__((ext_vector_type(4))) float f32x4;

#define TT 256
#define FF 20
#define BT 16
#define XCH 16                 // timesteps per x chunk
#define NXS 2                  // x ring slots
#define XROW 40                // x row stride (bf16)
#define XPLANE (BT * XROW)     // 640 per timestep
#define XSLOT (XCH * XPLANE)   // 10240 per chunk
#define H0S 72                 // h0 row stride (bf16), padded
#define H1S 40                 // h1/h2/h3 row stride
#define RD 8                   // h ring depth
#define NTHR 768
#define LOG2E 1.44269504f

__device__ __forceinline__ f32x4 mfma16(bf16x8 a, bf16x8 b, f32x4 c) {
  return __builtin_amdgcn_mfma_f32_16x16x32_bf16(a, b, c, 0, 0, 0);
}

__device__ __forceinline__ bf16x8 bfragW(const float* W, int Kreal, int N,
                                         int ncol, int kbase) {
  bf16x8 r;
#pragma unroll
  for (int j = 0; j < 8; ++j) {
    int k = kbase + j;
    r[j] = (__bf16)(k < Kreal ? W[k * N + ncol] : 0.f);
  }
  return r;
}

__device__ __forceinline__ int imin(int a, int b) { return a < b ? a : b; }

extern "C" __global__ void __launch_bounds__(NTHR, 3)
gru4(const float* __restrict__ inp, const float* __restrict__ Wemb,
     const float* __restrict__ k0, const float* __restrict__ rk0, const float* __restrict__ b0,
     const float* __restrict__ k1, const float* __restrict__ rk1, const float* __restrict__ b1,
     const float* __restrict__ k2, const float* __restrict__ rk2, const float* __restrict__ b2,
     const float* __restrict__ k3, const float* __restrict__ rk3, const float* __restrict__ b3,
     const float* __restrict__ Wd, const float* __restrict__ bd,
     float* __restrict__ out)
{
  __shared__ __align__(16) __bf16 x_ring[NXS * XSLOT];      // 40 KB
  __shared__ __align__(16) __bf16 h0ring[RD * BT * H0S];    // 18 KB
  __shared__ __align__(16) __bf16 h1ring[RD * BT * H1S];    // 10 KB
  __shared__ __align__(16) __bf16 h2ring[RD * BT * H1S];
  __shared__ __align__(16) __bf16 h3ring[RD * BT * H1S];
  __shared__ __align__(16) float h3f[BT * 32];
  __shared__ int flg[16];

  const int tid  = threadIdx.x;
  const int lane = tid & 63;
  const int w    = tid >> 6;        // wave 0..11
  const int col  = lane & 15;
  const int kb   = (lane >> 4) * 8;
  const int rowq = (lane >> 4) * 4;
  const long bbase = (long)blockIdx.x * BT;
  const float* binp = inp + bbase * TT * FF;

  bf16x8 zf;
#pragma unroll
  for (int j = 0; j < 8; ++j) zf[j] = (__bf16)0.f;

  // zero rings (h(-1) = 0) and flags
  for (int i = tid; i < RD * BT * H0S; i += NTHR) h0ring[i] = (__bf16)0.f;
  for (int i = tid; i < RD * BT * H1S; i += NTHR) {
    h1ring[i] = (__bf16)0.f; h2ring[i] = (__bf16)0.f; h3ring[i] = (__bf16)0.f;
  }
  if (tid < 16) flg[tid] = -1;
  __syncthreads();

  volatile int* vf = flg;

  if (w >= 10) {
    // ================= stager waves =================
    const int sid = w - 10;
    const int r0 = sid * 8;
    for (int c = 0; c < TT / XCH; ++c) {
      if (c >= NXS) {
        const int need = XCH * (c - (NXS - 1));   // all L0 past old tenant
        for (;;) {
          int m = imin(imin(vf[0], vf[1]), imin(vf[2], vf[3]));
          if (m >= need) break;
          __builtin_amdgcn_s_sleep(1);
        }
      }
      __bf16* xs = &x_ring[(c & (NXS - 1)) * XSLOT];
#pragma unroll
      for (int k = 0; k < 2; ++k) {
        const int task = k * 64 + lane;          // 0..127 = 8 rows x 16 t
        const int row = r0 + (task >> 4);
        const int tt  = task & 15;
        const float* p = binp + ((long)row * TT + c * XCH + tt) * FF;
        float4 v0 = *(const float4*)(p);
        float4 v1 = *(const float4*)(p + 4);
        float4 v2 = *(const float4*)(p + 8);
        float4 v3 = *(const float4*)(p + 12);
        float4 v4 = *(const float4*)(p + 16);
        float4 e  = *(const float4*)(Wemb + 4 * (int)v0.y);
        __bf16* d = xs + tt * XPLANE + row * XROW;
        bf16x8 q0 = {(__bf16)v0.x, (__bf16)v0.z, (__bf16)v0.w, (__bf16)v1.x,
                     (__bf16)v1.y, (__bf16)v1.z, (__bf16)v1.w, (__bf16)v2.x};
        bf16x8 q1 = {(__bf16)v2.y, (__bf16)v2.z, (__bf16)v2.w, (__bf16)v3.x,
                     (__bf16)v3.y, (__bf16)v3.z, (__bf16)v3.w, (__bf16)v4.x};
        bf16x8 q2 = {(__bf16)v4.y, (__bf16)v4.z, (__bf16)v4.w, (__bf16)e.x,
                     (__bf16)e.y,  (__bf16)e.z,  (__bf16)e.w,  (__bf16)0.f};
        *(bf16x8*)(d)      = q0;
        *(bf16x8*)(d + 8)  = q1;
        *(bf16x8*)(d + 16) = q2;
        *(bf16x8*)(d + 24) = zf;
      }
      __threadfence_block();                      // release
      if (lane == 0) vf[10 + sid] = c;
    }
  } else {
    // ================= recurrent waves =================
    int role, half;
    if (w < 4)      { role = 0; half = w; }
    else if (w < 6) { role = 2; half = w - 4; }
    else if (w < 8) { role = 1; half = w - 6; }
    else            { role = 3; half = w - 8; }
    const int uc = half * 16 + col;

    bf16x8 Wz0, Wz1, Wz2 = zf, Wr0, Wr1, Wr2 = zf, Wg0, Wg1, Wg2 = zf;
    float bz, br, bxh, bhh;
    const __bf16 *a0b = x_ring, *a1b = h0ring, *a2b = h0ring;
    int s0 = 0, s1 = 0, s2 = 0;
    __bf16* wb; int wS, wSlot;
    bool hasA2, g1in, isL0;
    int oB, oC, iB, iC, pB = 0, pC, myIdx;

    if (role == 0) {
      isL0 = true; hasA2 = true; g1in = false;
      Wz0 = bfragW(k0, 23, 192, uc, kb);
      Wz1 = bfragW(rk0, 64, 192, uc, kb);
      Wz2 = bfragW(rk0, 64, 192, uc, 32 + kb);
      Wr0 = bfragW(k0, 23, 192, 64 + uc, kb);
      Wr1 = bfragW(rk0, 64, 192, 64 + uc, kb);
      Wr2 = bfragW(rk0, 64, 192, 64 + uc, 32 + kb);
      Wg0 = bfragW(k0, 23, 192, 128 + uc, kb);
      Wg1 = bfragW(rk0, 64, 192, 128 + uc, kb);
      Wg2 = bfragW(rk0, 64, 192, 128 + uc, 32 + kb);
      bz  = b0[uc] + b0[192 + uc];
      br  = b0[64 + uc] + b0[192 + 64 + uc];
      bxh = b0[128 + uc];
      bhh = b0[192 + 128 + uc];
      a0b = &x_ring[col * XROW + kb];
      a1b = &h0ring[col * H0S + kb];      s1 = BT * H0S;
      a2b = &h0ring[col * H0S + 32 + kb]; s2 = BT * H0S;
      wb = &h0ring[rowq * H0S + uc]; wS = H0S; wSlot = BT * H0S;
      oB = 0; oC = 4; iB = 10; iC = 2; pB = 4; pC = 2; myIdx = half;
    } else if (role == 1) {
      isL0 = false; hasA2 = true; g1in = true;
      Wz0 = bfragW(k1, 64, 96, uc, kb);
      Wz1 = bfragW(k1, 64, 96, uc, 32 + kb);
      Wz2 = bfragW(rk1, 32, 96, uc, kb);
      Wr0 = bfragW(k1, 64, 96, 32 + uc, kb);
      Wr1 = bfragW(k1, 64, 96, 32 + uc, 32 + kb);
      Wr2 = bfragW(rk1, 32, 96, 32 + uc, kb);
      Wg0 = bfragW(k1, 64, 96, 64 + uc, kb);
      Wg1 = bfragW(k1, 64, 96, 64 + uc, 32 + kb);
      Wg2 = bfragW(rk1, 32, 96, 64 + uc, kb);
      bz  = b1[uc] + b1[96 + uc];
      br  = b1[32 + uc] + b1[96 + 32 + uc];
      bxh = b1[64 + uc];
      bhh = b1[96 + 64 + uc];
      a0b = &h0ring[col * H0S + kb];      s0 = BT * H0S;
      a1b = &h0ring[col * H0S + 32 + kb]; s1 = BT * H0S;
      a2b = &h1ring[col * H1S + kb];      s2 = BT * H1S;
      wb = &h1ring[rowq * H1S + uc]; wS = H1S; wSlot = BT * H1S;
      oB = 4; oC = 2; iB = 0; iC = 4; pB = 6; pC = 2; myIdx = 4 + half;
    } else if (role == 2) {
      isL0 = false; hasA2 = false; g1in = false;
      Wz0 = bfragW(k2, 32, 96, uc, kb);
      Wz1 = bfragW(rk2, 32, 96, uc, kb);
      Wr0 = bfragW(k2, 32, 96, 32 + uc, kb);
      Wr1 = bfragW(rk2, 32, 96, 32 + uc, kb);
      Wg0 = bfragW(k2, 32, 96, 64 + uc, kb);
      Wg1 = bfragW(rk2, 32, 96, 64 + uc, kb);
      bz  = b2[uc] + b2[96 + uc];
      br  = b2[32 + uc] + b2[96 + 32 + uc];
      bxh = b2[64 + uc];
      bhh = b2[96 + 64 + uc];
      a0b = &h1ring[col * H1S + kb]; s0 = BT * H1S;
      a1b = &h2ring[col * H1S + kb]; s1 = BT * H1S;
      wb = &h2ring[rowq * H1S + uc]; wS = H1S; wSlot = BT * H1S;
      oB = 6; oC = 2; iB = 4; iC = 2; pB = 8; pC = 2; myIdx = 6 + half;
    } else {
      isL0 = false; hasA2 = false; g1in = false;
      Wz0 = bfragW(k3, 32, 96, uc, kb);
      Wz1 = bfragW(rk3, 32, 96, uc, kb);
      Wr0 = bfragW(k3, 32, 96, 32 + uc, kb);
      Wr1 = bfragW(rk3, 32, 96, 32 + uc, kb);
      Wg0 = bfragW(k3, 32, 96, 64 + uc, kb);
      Wg1 = bfragW(rk3, 32, 96, 64 + uc, kb);
      bz  = b3[uc] + b3[96 + uc];
      br  = b3[32 + uc] + b3[96 + 32 + uc];
      bxh = b3[64 + uc];
      bhh = b3[96 + 64 + uc];
      a0b = &h2ring[col * H1S + kb]; s0 = BT * H1S;
      a1b = &h3ring[col * H1S + kb]; s1 = BT * H1S;
      wb = &h3ring[rowq * H1S + uc]; wS = H1S; wSlot = BT * H1S;
      oB = 8; oC = 2; iB = 6; iC = 2; pC = 0; myIdx = 8 + half;
    }
    const bool a1prev = (role != 1);   // A1 slot: t-1 except L1 (input side, t)

    float hreg[4] = {0.f, 0.f, 0.f, 0.f};

    for (int t = 0; t < TT; ++t) {
      const int inNeed = isL0 ? (t >> 4) : t;
      // ---- spin on dependencies (usually passes first try) ----
      for (;;) {
        int m = imin(vf[oB], vf[oB + 1]);
        if (oC == 4) m = imin(m, imin(vf[oB + 2], vf[oB + 3]));
        int mi = imin(vf[iB], vf[iB + 1]);
        if (iC == 4) mi = imin(mi, imin(vf[iB + 2], vf[iB + 3]));
        bool ok = (m >= t - 1) && (mi >= inNeed);
        if (pC) ok = ok && (imin(vf[pB], vf[pB + 1]) >= t - RD);
        if (ok) break;
        __builtin_amdgcn_s_sleep(1);
      }
      __threadfence_block();                      // acquire

      const int sPrev = (t - 1) & (RD - 1);
      const int sCur  = t & (RD - 1);
      bf16x8 A0, A1, A2 = zf;
      if (isL0)
        A0 = *(const bf16x8*)(a0b + ((t >> 4) & (NXS - 1)) * XSLOT
                                  + (t & (XCH - 1)) * XPLANE);
      else
        A0 = *(const bf16x8*)(a0b + sCur * s0);
      A1 = *(const bf16x8*)(a1b + (a1prev ? sPrev : sCur) * s1);
      if (hasA2) A2 = *(const bf16x8*)(a2b + sPrev * s2);

      f32x4 az  = {bz, bz, bz, bz};
      f32x4 ar  = {br, br, br, br};
      f32x4 axh = {bxh, bxh, bxh, bxh};
      f32x4 ahh = {bhh, bhh, bhh, bhh};
      az = mfma16(A0, Wz0, az);
      ar = mfma16(A0, Wr0, ar);
      axh = mfma16(A0, Wg0, axh);
      az = mfma16(A1, Wz1, az);
      ar = mfma16(A1, Wr1, ar);
      if (g1in) axh = mfma16(A1, Wg1, axh);
      else      ahh = mfma16(A1, Wg1, ahh);
      if (hasA2) {
        az = mfma16(A2, Wz2, az);
        ar = mfma16(A2, Wr2, ar);
        ahh = mfma16(A2, Wg2, ahh);
      }

      __bf16* wr = wb + sCur * wSlot;
#define GATE(r) { \
        float yz = fminf(fmaxf(az[r], -44.f), 44.f) * -LOG2E; \
        float yr = fminf(fmaxf(ar[r], -44.f), 44.f) * -LOG2E; \
        float Ez = __builtin_amdgcn_exp2f(yz); \
        float Er = __builtin_amdgcn_exp2f(yr); \
        float dz = 1.f + Ez, dr = 1.f + Er; \
        float inv = __builtin_amdgcn_rcpf(dz * dr); \
        float z  = inv * dr; \
        float rg = inv * dz; \
        float uu = fmaf(rg, ahh[r], axh[r]); \
        float Eg = __builtin_amdgcn_exp2f(uu * (-2.f * LOG2E)); \
        float hc = fmaf(2.f, __builtin_amdgcn_rcpf(1.f + Eg), -1.f); \
        float hn = fmaf(z, hreg[r] - hc, hc); \
        hreg[r] = hn; \
        wr[(r) * wS] = (__bf16)hn; }
      GATE(0); GATE(1); GATE(2); GATE(3);
#undef GATE

      __threadfence_block();                      // release
      if (lane == 0) vf[myIdx] = t;
    }

    if (role == 3) {
#pragma unroll
      for (int r = 0; r < 4; ++r)
        h3f[(rowq + r) * 32 + uc] = hreg[r];
    }
  }

  __syncthreads();   // single end-of-kernel barrier

  // ------------- epilogue: logits + softmax -------------
  if (tid < BT) {
    float l0 = bd[0], l1 = bd[1];
#pragma unroll
    for (int u = 0; u < 32; ++u) {
      float h = h3f[tid * 32 + u];
      l0 = fmaf(h, Wd[2 * u], l0);
      l1 = fmaf(h, Wd[2 * u + 1], l1);
    }
    float m = fmaxf(l0, l1);
    float e0 = __builtin_amdgcn_exp2f((l0 - m) * LOG2E);
    float e1 = __builtin_amdgcn_exp2f((l1 - m) * LOG2E);
    float inv = 1.f / (e0 + e1);
    out[(bbase + tid) * 2 + 0] = e0 * inv;
    out[(bbase + tid) * 2 + 1] = e1 * inv;
  }
}

extern "C" void kernel_launch(void* const* d_in, const int* in_sizes, int n_in,
                              void* d_out, int out_size, void* d_ws, size_t ws_size,
                              hipStream_t stream) {
  const float* inp  = (const float*)d_in[0];
  const float* Wemb = (const float*)d_in[1];
  const float* k0   = (const float*)d_in[2];
  const float* rk0  = (const float*)d_in[3];
  const float* b0   = (const float*)d_in[4];
  const float* k1   = (const float*)d_in[5];
  const float* rk1  = (const float*)d_in[6];
  const float* b1   = (const float*)d_in[7];
  const float* k2   = (const float*)d_in[8];
  const float* rk2  = (const float*)d_in[9];
  const float* b2   = (const float*)d_in[10];
  const float* k3   = (const float*)d_in[11];
  const float* rk3  = (const float*)d_in[12];
  const float* b3   = (const float*)d_in[13];
  const float* Wd   = (const float*)d_in[14];
  const float* bd   = (const float*)d_in[15];
  float* out = (float*)d_out;

  const int Btot = in_sizes[0] / (TT * FF);   // 4096
  dim3 grid(Btot / BT);                       // 256 blocks
  gru4<<<grid, NTHR, 0, stream>>>(inp, Wemb, k0, rk0, b0, k1, rk1, b1,
                                  k2, rk2, b2, k3, rk3, b3, Wd, bd, out);
}